// Round 10
// baseline (405.842 us; speedup 1.0000x reference)
//
#include <hip/hip_runtime.h>
#include <hip/hip_fp16.h>
#include <math.h>

#define THREADS 256
#define KC 32
#define BSHIFT 9          // 512 nodes per bucket
#define BNODES (1 << BSHIFT)
#define NB_MAX 256        // max buckets (N<=131072)
#define ECHUNK 4096       // edges per block in binning kernels

__device__ __forceinline__ float clipf(float v){ return fminf(fmaxf(v, -10.f), 10.f); }

typedef __attribute__((ext_vector_type(8))) short bf16x8;
typedef __attribute__((ext_vector_type(8))) _Float16 f16x8;
typedef __attribute__((ext_vector_type(4))) float f32x4;
typedef __attribute__((ext_vector_type(16))) float f32x16;

// split fp32 into bf16 hi + bf16 lo (3-term split-GEMM decomposition)
__device__ __forceinline__ void split_bf16(float f, short& hi, short& lo){
    union { float f; unsigned u; } a; a.f = f;
    unsigned r = (a.u + 0x7FFFu + ((a.u >> 16) & 1u)) & 0xFFFF0000u;
    hi = (short)(r >> 16);
    union { unsigned u; float f; } b; b.u = r;
    float rem = f - b.f;
    union { float f; unsigned u; } c; c.f = rem;
    unsigned r2 = c.u + 0x7FFFu + ((c.u >> 16) & 1u);
    lo = (short)(r2 >> 16);
}

// fragment-linear ("packed") layouts: a wave-load of one MFMA fragment is
// base + lane*16B, fully coalesced. Pure storage permutation (same values
// land in the same lanes -> bitwise-identical MFMA inputs).
// W: [ncols][256] -> tile t=n/16, kb=k/32, lane=((k>>3)&3)*16+(n&15), j=k&7
__device__ __forceinline__ long wpk(int n, int k){
    return ((((long)(n >> 4)*8 + (k >> 5))*64) + ((k >> 3) & 3)*16 + (n & 15))*8 + (k & 7);
}
// A: [B][128] -> rb=r/16, kb=k/32 (k in [0,128)), lane=((k>>3)&3)*16+(r&15), j=k&7
__device__ __forceinline__ long apk(int r, int k){
    return ((((long)(r >> 4)*4 + (k >> 5))*64) + ((k >> 3) & 3)*16 + (r & 15))*8 + (k & 7);
}

// ---------------------------------------------------------------- fused setup:
__global__ __launch_bounds__(256) void setup_k(
        const float* __restrict__ x, __half* __restrict__ xh, long n8, int nConv,
        const float* __restrict__ w_l0, const float* __restrict__ w_r0,
        const float* __restrict__ w_l1, const float* __restrict__ w_r1,
        const float* __restrict__ wc0,  const float* __restrict__ wc1,
        const float* __restrict__ w_ih, const float* __restrict__ b_ih, const float* __restrict__ b_hh,
        __half* __restrict__ wt0f,
        short* __restrict__ wt1h, short* __restrict__ wt1l,
        short* __restrict__ wgh,  short* __restrict__ wgl,
        short* __restrict__ wc0h, short* __restrict__ wc0l,
        float* __restrict__ wtc1, float* __restrict__ bsum, float* __restrict__ ohtab, int nPrep,
        const int* __restrict__ uid, int B, int* __restrict__ flag, int nFlag,
        const int* __restrict__ dstv, int E, int nbuckets, int* __restrict__ bcnt){
    __shared__ int hsh[NB_MAX];
    int b = blockIdx.x;
    if (b < nConv){
        long t = (long)b*256 + threadIdx.x;
        if (t >= n8) return;
        long i = t*8;
        float4 a = *(const float4*)(x + i);
        float4 bb = *(const float4*)(x + i + 4);
        union { __half2 h[4]; float4 f; } u;
        u.h[0] = __floats2half2_rn(a.x, a.y);
        u.h[1] = __floats2half2_rn(a.z, a.w);
        u.h[2] = __floats2half2_rn(bb.x, bb.y);
        u.h[3] = __floats2half2_rn(bb.z, bb.w);
        *(float4*)(xh + i) = u.f;
    } else if (b < nConv + nPrep){
        int idx = (b - nConv)*256 + threadIdx.x;
        if (idx < 32768){
            int n = idx >> 8, k = idx & 255;
            float f = (k < 128) ? w_l0[n*128 + k] : w_r0[n*128 + (k - 128)];
            wt0f[idx] = __float2half(f);
        } else if (idx < 65536){
            int i = idx - 32768;
            int n = i >> 8, k = i & 255;
            float f = (k < 128) ? w_l1[n*128 + k] : w_r1[n*128 + (k - 128)];
            short h, l; split_bf16(f, h, l);
            long d = wpk(n, k);
            wt1h[d] = h; wt1l[d] = l;
        } else if (idx < 163840){
            int i = idx - 65536;
            int n = i >> 8, k = i & 255;       // n in [0,384)
            int j = n + ((n >= 128) ? 128 : 0);
            float f = w_ih[j*261 + k];
            short h, l; split_bf16(f, h, l);
            long d = wpk(n, k);
            wgh[d] = h; wgl[d] = l;
        } else if (idx < 196608){
            int i = idx - 163840;
            int n = i >> 8, k = i & 255;
            float f = wc0[i];                  // [128][256] already [n][k]
            short h, l; split_bf16(f, h, l);
            long d = wpk(n, k);
            wc0h[d] = h; wc0l[d] = l;
        } else if (idx < 204800){
            int i = idx - 196608;
            int j = i >> 7, k = i & 127;
            wtc1[k*64 + j] = wc1[j*128 + k];
        } else if (idx < 205184){
            int jj = idx - 204800;
            int j = jj + ((jj >= 128) ? 128 : 0);
            bsum[jj] = b_ih[j] + b_hh[j];
            for (int r = 0; r < 5; ++r) ohtab[r*384 + jj] = w_ih[j*261 + 256 + r];
        }
    } else if (b < nConv + nPrep + nFlag){
        int i = (b - nConv - nPrep)*256 + threadIdx.x;
        if (i < B) flag[uid[i]] = 1;
    } else {
        int lb = b - nConv - nPrep - nFlag;
        int b0 = lb * ECHUNK;
        int b1 = min(b0 + ECHUNK, E);
        for (int i = threadIdx.x; i < nbuckets; i += 256) hsh[i] = 0;
        __syncthreads();
        for (int i = b0 + threadIdx.x; i < b1; i += 256)
            atomicAdd(&hsh[dstv[i] >> BSHIFT], 1);
        __syncthreads();
        for (int i = threadIdx.x; i < nbuckets; i += 256){
            int c = hsh[i];
            if (c) atomicAdd(&bcnt[i], c);
        }
    }
}

// ---------------------------------------------------------------- CSR build (bucket-first)
// block 0: bucket prefix scan; blocks 1..: compact user flags -> ulist
__global__ __launch_bounds__(256) void scan_compact(const int* __restrict__ bcnt, int nb, int E, int N,
                                                    int* __restrict__ boffs, int* __restrict__ bcur, int* __restrict__ row_start,
                                                    const int* __restrict__ flag, int* __restrict__ list, int* __restrict__ cnt){
    if (blockIdx.x == 0){
        __shared__ int sh[256];
        int t = threadIdx.x;
        int v = (t < nb) ? bcnt[t] : 0;
        sh[t] = v; __syncthreads();
        for (int off = 1; off < 256; off <<= 1){
            int u = (t >= off) ? sh[t-off] : 0;
            __syncthreads();
            sh[t] += u;
            __syncthreads();
        }
        int ex = sh[t] - v;
        if (t < nb){ boffs[t] = ex; bcur[t] = ex; }
        if (t == 0){ boffs[nb] = E; row_start[N] = E; }
    } else {
        int i = (blockIdx.x - 1)*256 + threadIdx.x;
        if (i < N && flag[i]){ int p = atomicAdd(cnt, 1); list[p] = i; }
    }
}

__global__ __launch_bounds__(256) void bin_edges_priv(const int* __restrict__ srcv, const int* __restrict__ dstv, int E,
                                                      int nbuckets, int* __restrict__ bcur, int2* __restrict__ pairs){
    __shared__ int cnt[NB_MAX];
    __shared__ int base[NB_MAX];
    int b0 = blockIdx.x * ECHUNK;
    int b1 = min(b0 + ECHUNK, E);
    for (int i = threadIdx.x; i < nbuckets; i += 256) cnt[i] = 0;
    __syncthreads();
    for (int i = b0 + threadIdx.x; i < b1; i += 256)
        atomicAdd(&cnt[dstv[i] >> BSHIFT], 1);
    __syncthreads();
    for (int i = threadIdx.x; i < nbuckets; i += 256){
        int c = cnt[i];
        base[i] = c ? atomicAdd(&bcur[i], c) : 0;
    }
    __syncthreads();
    for (int i = threadIdx.x; i < nbuckets; i += 256) cnt[i] = 0;
    __syncthreads();
    for (int i = b0 + threadIdx.x; i < b1; i += 256){
        int d = dstv[i];
        int bk = d >> BSHIFT;
        int loc = atomicAdd(&cnt[bk], 1);
        pairs[base[bk] + loc] = make_int2(d, srcv[i]);
    }
}

__global__ __launch_bounds__(256) void fill_bucket2(const int2* __restrict__ pairs, const int* __restrict__ boffs,
                                                    int* __restrict__ row_start, int* __restrict__ col_idx, int N){
    __shared__ int cur[BNODES];
    __shared__ int sh[256];
    int b  = blockIdx.x;
    int n0 = b << BSHIFT;
    int nn = min(BNODES, N - n0);
    int s = boffs[b], e = boffs[b+1];
    int t = threadIdx.x;
    cur[2*t]   = 0;
    cur[2*t+1] = 0;
    __syncthreads();
    for (int i = s + t; i < e; i += 256)
        atomicAdd(&cur[pairs[i].x - n0], 1);
    __syncthreads();
    int c0 = cur[2*t], c1 = cur[2*t+1];
    int s2 = c0 + c1;
    sh[t] = s2; __syncthreads();
    for (int off = 1; off < 256; off <<= 1){
        int u = (t >= off) ? sh[t-off] : 0;
        __syncthreads();
        sh[t] += u;
        __syncthreads();
    }
    int ex = sh[t] - s2;
    __syncthreads();
    cur[2*t]   = s + ex;
    cur[2*t+1] = s + ex + c0;
    __syncthreads();
    for (int i = t; i < nn; i += 256) row_start[n0 + i] = cur[i];
    __syncthreads();
    for (int i = s + t; i < e; i += 256){
        int2 p = pairs[i];
        int loc = atomicAdd(&cur[p.x - n0], 1);
        col_idx[loc] = p.y;
    }
}

// ---------------------------------------------------------------- fp16 mean aggregation (fp32 accum)
__device__ __forceinline__ void accumh(float4& a0, float4& a1, float4 v){
    const __half2* h = (const __half2*)&v;
    float2 f0 = __half22float2(h[0]);
    float2 f1 = __half22float2(h[1]);
    float2 f2 = __half22float2(h[2]);
    float2 f3 = __half22float2(h[3]);
    a0.x += f0.x; a0.y += f0.y; a0.z += f1.x; a0.w += f1.y;
    a1.x += f2.x; a1.y += f2.y; a1.z += f3.x; a1.w += f3.y;
}

// group-per-node aggregation body: one 16-lane group owns one node.
// Lane sl owns features [sl*8, sl*8+8). OM=0: fp16 row out; OM=1: split bf16 out.
template<int OM>
__device__ __forceinline__ void agg_group(const __half* __restrict__ feat, const int* __restrict__ row_start,
                                          const int* __restrict__ col_idx, void* __restrict__ o1, void* __restrict__ o2,
                                          int node, int sl){
    int s = row_start[node], e = row_start[node+1];
    const float4* f16 = (const float4*)feat;
    float4 a0 = make_float4(0.f,0.f,0.f,0.f);
    float4 a1 = make_float4(0.f,0.f,0.f,0.f);
    int i = s;
    for (; i + 7 < e; i += 8){                 // 8 loads in flight
        int c0 = col_idx[i+0];
        int c1 = col_idx[i+1];
        int c2 = col_idx[i+2];
        int c3 = col_idx[i+3];
        int c4 = col_idx[i+4];
        int c5 = col_idx[i+5];
        int c6 = col_idx[i+6];
        int c7 = col_idx[i+7];
        float4 v0 = f16[(long)c0*16 + sl];
        float4 v1 = f16[(long)c1*16 + sl];
        float4 v2 = f16[(long)c2*16 + sl];
        float4 v3 = f16[(long)c3*16 + sl];
        float4 v4 = f16[(long)c4*16 + sl];
        float4 v5 = f16[(long)c5*16 + sl];
        float4 v6 = f16[(long)c6*16 + sl];
        float4 v7 = f16[(long)c7*16 + sl];
        accumh(a0, a1, v0);
        accumh(a0, a1, v1);
        accumh(a0, a1, v2);
        accumh(a0, a1, v3);
        accumh(a0, a1, v4);
        accumh(a0, a1, v5);
        accumh(a0, a1, v6);
        accumh(a0, a1, v7);
    }
    if (i + 3 < e){                            // 4-deep tail
        int c0 = col_idx[i+0];
        int c1 = col_idx[i+1];
        int c2 = col_idx[i+2];
        int c3 = col_idx[i+3];
        float4 v0 = f16[(long)c0*16 + sl];
        float4 v1 = f16[(long)c1*16 + sl];
        float4 v2 = f16[(long)c2*16 + sl];
        float4 v3 = f16[(long)c3*16 + sl];
        accumh(a0, a1, v0);
        accumh(a0, a1, v1);
        accumh(a0, a1, v2);
        accumh(a0, a1, v3);
        i += 4;
    }
    if (i + 1 < e){                            // 2-deep tail
        int c0 = col_idx[i+0];
        int c1 = col_idx[i+1];
        float4 v0 = f16[(long)c0*16 + sl];
        float4 v1 = f16[(long)c1*16 + sl];
        accumh(a0, a1, v0);
        accumh(a0, a1, v1);
        i += 2;
    }
    if (i < e){                                // final single
        float4 v0 = f16[(long)col_idx[i]*16 + sl];
        accumh(a0, a1, v0);
    }
    float inv = 1.f / fmaxf((float)(e - s), 1.f);
    a0.x *= inv; a0.y *= inv; a0.z *= inv; a0.w *= inv;
    a1.x *= inv; a1.y *= inv; a1.z *= inv; a1.w *= inv;
    if constexpr (OM == 0){
        union { __half2 h[4]; int4 v; } u;
        u.h[0] = __floats2half2_rn(a0.x, a0.y);
        u.h[1] = __floats2half2_rn(a0.z, a0.w);
        u.h[2] = __floats2half2_rn(a1.x, a1.y);
        u.h[3] = __floats2half2_rn(a1.z, a1.w);
        *(int4*)((__half*)o1 + (long)node*128 + sl*8) = u.v;
    } else {
        float vals[8] = {a0.x, a0.y, a0.z, a0.w, a1.x, a1.y, a1.z, a1.w};
        union { short s[8]; int4 v; } uh, ul;
        #pragma unroll
        for (int j = 0; j < 8; ++j) split_bf16(vals[j], uh.s[j], ul.s[j]);
        *(int4*)((short*)o1 + (long)node*128 + sl*8) = uh.v;
        *(int4*)((short*)o2 + (long)node*128 + sl*8) = ul.v;
    }
}

__global__ __launch_bounds__(256) void aggregate_h16(const __half* __restrict__ feat, const int* __restrict__ row_start,
                                                     const int* __restrict__ col_idx,
                                                     __half* __restrict__ outmean, int N){
    int node = (blockIdx.x*256 + threadIdx.x) >> 4;   // one 16-lane group per node
    if (node >= N) return;
    agg_group<0>(feat, row_start, col_idx, outmean, nullptr, node, threadIdx.x & 15);
}

// fused: user-node aggregation (split output, mean1 row-major node-indexed)
// + per-user gather/split of xh/hh rows (PACKED batch-row layout)
__global__ __launch_bounds__(256) void aggkh_usplit(const __half* __restrict__ hh, const __half* __restrict__ xh,
                                                    const int* __restrict__ row_start, const int* __restrict__ col_idx,
                                                    const int* __restrict__ list, const int* __restrict__ cnt,
                                                    const int* __restrict__ uid, int B,
                                                    short* __restrict__ mean1h, short* __restrict__ mean1l,
                                                    short* __restrict__ xuh, short* __restrict__ xul,
                                                    short* __restrict__ huh, short* __restrict__ hul, int gAgg){
    int b = blockIdx.x;
    if (b < gAgg){
        int w = (b*256 + threadIdx.x) >> 4;
        if (w >= *cnt) return;
        agg_group<1>(hh, row_start, col_idx, mean1h, mean1l, list[w], threadIdx.x & 15);
    } else {
        int t = (b - gAgg)*256 + threadIdx.x;
        if (t >= B*32) return;
        int r = t >> 5, k4 = t & 31;
        long so = (long)uid[r]*128 + k4*4;
        long dofs = apk(r, k4*4);   // int2 spans j..j+3 within one packed octet
        union { int2 p; __half h[4]; } ux, uh;
        ux.p = *(const int2*)(xh + so);
        uh.p = *(const int2*)(hh + so);
        union { short s[4]; int2 p; } xa, xb, ha, hb;
        #pragma unroll
        for (int j = 0; j < 4; ++j){
            float vx = clipf(__half2float(ux.h[j]));
            split_bf16(vx, xa.s[j], xb.s[j]);
            float vh = __half2float(uh.h[j]);
            split_bf16(vh, ha.s[j], hb.s[j]);
        }
        *(int2*)(xuh + dofs) = xa.p;
        *(int2*)(xul + dofs) = xb.p;
        *(int2*)(huh + dofs) = ha.p;
        *(int2*)(hul + dofs) = hb.p;
    }
}

// ---------------------------------------------------------------- layer-0 GEMM via f16 32x32x16 MFMA (single-term)
// hh = relu([mean0h|xh] @ wt0^T + b_l0); all A inputs already fp16 -> raw int4 staging.
// (r8 proven staging — the async global_load_lds experiment is parked.)
__global__ __launch_bounds__(256) void gemm32_mfma(const __half* __restrict__ mean0h, const __half* __restrict__ xh,
                                                   const __half* __restrict__ wf,
                                                   const float* __restrict__ bias,
                                                   __half* __restrict__ outh, int M){
    __shared__ __align__(16) _Float16 As[8*64*8];   // 8 regions x 64 lanes x 8 halfs = 8 KB
    __shared__ __align__(16) _Float16 Ws[8*64*8];

    const int tid  = threadIdx.x;
    const int row0 = blockIdx.x * 128;
    const int wave = tid >> 6, lane = tid & 63;
    const int wr = wave >> 1, wc = wave & 1;
    const int c32 = lane & 31, gg = lane >> 5;

    f32x16 acc[2][2];
    #pragma unroll
    for (int rm = 0; rm < 2; ++rm)
        #pragma unroll
        for (int cn = 0; cn < 2; ++cn)
            #pragma unroll
            for (int r = 0; r < 16; ++r) acc[rm][cn][r] = 0.f;

    for (int ko = 0; ko < 256; ko += KC){
        // stage A (128 rows x 32 k) — pure int4 copies
        #pragma unroll
        for (int it = 0; it < 2; ++it){
            int cid = it*256 + tid;
            int row = cid >> 2, s = (cid >> 1) & 1, g = cid & 1;
            int grow = row0 + row; if (grow >= M) grow = M - 1;
            int k = ko + s*16 + g*8;
            int slot = ((s*4 + (row >> 5))*64 + g*32 + (row & 31)) * 8;
            const __half* p = (k < 128) ? (mean0h + (long)grow*128 + k) : (xh + (long)grow*128 + (k - 128));
            *(int4*)&As[slot] = *(const int4*)p;
        }
        // stage W (128 cols x 32 k), fp16 weights
        #pragma unroll
        for (int it = 0; it < 2; ++it){
            int cid = it*256 + tid;
            int n = cid >> 2, s = (cid >> 1) & 1, g = cid & 1;
            int k = ko + s*16 + g*8;
            int4 vh = *(const int4*)(wf + (long)n*256 + k);
            int slot = ((s*4 + (n >> 5))*64 + g*32 + (n & 31)) * 8;
            *(int4*)&Ws[slot] = vh;
        }
        __syncthreads();

        #pragma unroll
        for (int s = 0; s < 2; ++s){
            f16x8 ah[2], bh[2];
            #pragma unroll
            for (int rm = 0; rm < 2; ++rm){
                int reg = (s*4 + 2*wr + rm)*64 + lane;
                ah[rm] = *(const f16x8*)&As[reg*8];
            }
            #pragma unroll
            for (int cn = 0; cn < 2; ++cn){
                int reg = (s*4 + 2*wc + cn)*64 + lane;
                bh[cn] = *(const f16x8*)&Ws[reg*8];
            }
            #pragma unroll
            for (int rm = 0; rm < 2; ++rm)
                #pragma unroll
                for (int cn = 0; cn < 2; ++cn)
                    acc[rm][cn] = __builtin_amdgcn_mfma_f32_32x32x16_f16(ah[rm], bh[cn], acc[rm][cn], 0, 0, 0);
        }
        __syncthreads();
    }

    // epilogue: C/D row = (reg&3) + 8*(reg>>2) + 4*(lane>>5), col = lane&31 (m74/m101)
    #pragma unroll
    for (int rm = 0; rm < 2; ++rm)
        #pragma unroll
        for (int cn = 0; cn < 2; ++cn){
            int col = (2*wc + cn)*32 + c32;
            float b = bias[col];
            #pragma unroll
            for (int r = 0; r < 16; ++r){
                int row = row0 + (2*wr + rm)*32 + (r & 3) + 8*(r >> 2) + 4*gg;
                if (row < M)
                    outh[(long)row*128 + col] = __float2half(fmaxf(acc[rm][cn][r] + b, 0.f));
            }
        }
}

// ---------------------------------------------------------------- B-row GEMMs: no LDS/barriers, PACKED coalesced loads
// Block = 4 waves = 64 rows x 128 cols. Wave = 32 rows x 64 cols (2 m-tiles x 4 t-tiles).
// MODE 1: ue = clip([mean1|hh[uid]] @ wt1^T + b_l1)   A0 node-gathered (scattered); OUT packed split bf16
// MODE 2: gates_cg = [ue|xu] @ wg_cg^T + bsum + ohtab cg = blockIdx.y; OUT fp32 [B][384]
template<int MODE>
__global__ __launch_bounds__(256) void gemmM_mfma(const short* __restrict__ aH0, const short* __restrict__ aL0,
                                                  const short* __restrict__ aH1, const short* __restrict__ aL1,
                                                  const int* __restrict__ g,
                                                  const short* __restrict__ wh, const short* __restrict__ wl,
                                                  const float* __restrict__ bias, const float* __restrict__ ohtab,
                                                  const int* __restrict__ roles,
                                                  float* __restrict__ out, short* __restrict__ outH, short* __restrict__ outL,
                                                  int ncolsOut, int M){
    const int lane = threadIdx.x & 63;
    const int wave = threadIdx.x >> 6;
    const int lm = lane & 15, quad = lane >> 4;
    const int row0 = blockIdx.x * 64 + (wave & 1) * 32;   // wave's 32-row span
    const int tg0  = blockIdx.y * 8 + (wave >> 1) * 4;    // wave's first 16-col tile index

    long r0[2];
    if constexpr (MODE == 1){
        #pragma unroll
        for (int m = 0; m < 2; ++m){
            int ar = row0 + m*16 + lm; if (ar >= M) ar = M - 1;
            r0[m] = (long)g[ar];
        }
    }

    f32x4 acc[2][4];
    #pragma unroll
    for (int m = 0; m < 2; ++m)
        #pragma unroll
        for (int t = 0; t < 4; ++t) acc[m][t] = (f32x4){0.f, 0.f, 0.f, 0.f};

    #pragma unroll
    for (int ko = 0; ko < 256; ko += KC){
        const bool lo = (ko < 128);
        const int kk0 = lo ? ko : ko - 128;
        bf16x8 ah[2], al[2];
        #pragma unroll
        for (int m = 0; m < 2; ++m){
            if (MODE == 1 && lo){
                // mean1: node-indexed row-major, gathered (scattered load)
                ah[m] = *(const bf16x8*)(aH0 + r0[m]*128 + kk0 + quad*8);
                al[m] = *(const bf16x8*)(aL0 + r0[m]*128 + kk0 + quad*8);
            } else {
                const short* sH = lo ? aH0 : aH1;
                const short* sL = lo ? aL0 : aL1;
                long ab = ((((long)((row0 >> 4) + m)*4 + (kk0 >> 5))*64) + lane)*8;
                ah[m] = *(const bf16x8*)(sH + ab);
                al[m] = *(const bf16x8*)(sL + ab);
            }
        }
        #pragma unroll
        for (int t = 0; t < 4; ++t){
            long wb = ((((long)(tg0 + t)*8 + (ko >> 5))*64) + lane)*8;
            bf16x8 bh = *(const bf16x8*)(wh + wb);
            bf16x8 bl = *(const bf16x8*)(wl + wb);
            #pragma unroll
            for (int m = 0; m < 2; ++m){
                acc[m][t] = __builtin_amdgcn_mfma_f32_16x16x32_bf16(ah[m], bh, acc[m][t], 0, 0, 0);
                acc[m][t] = __builtin_amdgcn_mfma_f32_16x16x32_bf16(ah[m], bl, acc[m][t], 0, 0, 0);
                acc[m][t] = __builtin_amdgcn_mfma_f32_16x16x32_bf16(al[m], bh, acc[m][t], 0, 0, 0);
            }
        }
    }

    #pragma unroll
    for (int m = 0; m < 2; ++m){
        #pragma unroll
        for (int t = 0; t < 4; ++t){
            int gcol = (tg0 + t)*16 + lm;
            float b = bias[gcol];
            #pragma unroll
            for (int r = 0; r < 4; ++r){
                int row = row0 + m*16 + quad*4 + r;
                if (row >= M) continue;
                float v = acc[m][t][r] + b;
                if constexpr (MODE == 1){
                    v = clipf(v);
                    short h, l; split_bf16(v, h, l);
                    long d = apk(row, gcol);
                    outH[d] = h;
                    outL[d] = l;
                } else {
                    out[(long)row*ncolsOut + gcol] = v + ohtab[roles[row]*384 + gcol];
                }
            }
        }
    }
}

// ---------------------------------------------------------------- fused: lstm activation (LDS) + z0 GEMM + z1 + classifier
// Block = 64 batch rows, 256 threads. Phase 0: lstm = act(gates) -> LDS split
// bf16 in fragment-linear layout (identical values/lanes as the old packed
// global path). Phase 1: z0 = relu([ue|lstm] @ wc0^T + bc0) -> LDS. Phase 2:
// z1 = relu(z0 @ wtc1 + bc1); out = z1 @ wc2^T + bc2.
__global__ __launch_bounds__(256) void gemmM3_tail(const short* __restrict__ ueh, const short* __restrict__ uel,
                                                   const float* __restrict__ gates,
                                                   const short* __restrict__ wh, const short* __restrict__ wl,
                                                   const float* __restrict__ bias,
                                                   const float* __restrict__ wt, const float* __restrict__ bias1,
                                                   const float* __restrict__ wc2, const float* __restrict__ bc2,
                                                   float* __restrict__ out, int M){
    constexpr int BM = 64;
    constexpr int BN = 64;
    constexpr int TN = 4;
    constexpr int CT = BN / TN;          // 16
    constexpr int RT = THREADS / CT;     // 16
    constexpr int TM = BM / RT;          // 4
    constexpr int AST = BM + 4;

    __shared__ __align__(16) short Lh[64*128];     // lstm hi (fragment-linear, block-local)
    __shared__ __align__(16) short Ll[64*128];     // lstm lo
    __shared__ __align__(16) float z0L[64][132];   // z0 tile (row-major, padded)
    __shared__ __align__(16) float As[KC][AST];
    __shared__ __align__(16) float Ws[KC][BN];
    __shared__ float Zs[BM][BN + 1];
    __shared__ float Wc[5][64];

    const int tid  = threadIdx.x;
    const int lane = tid & 63, wave = tid >> 6;
    const int lm = lane & 15, quad = lane >> 4;
    const int row0 = blockIdx.x * 64;

    for (int i = tid; i < 320; i += THREADS) Wc[i >> 6][i & 63] = wc2[i];

    // ---- phase 0: LSTM activation -> LDS (bitwise-identical chain to lstm_act)
    {
        int r = tid >> 2;                     // 0..63
        int grow = row0 + r; if (grow >= M) grow = M - 1;
        const float* gr = gates + (long)grow*384;
        int j0 = (tid & 3)*32;
        for (int jj = 0; jj < 32; ++jj){
            int j = j0 + jj;
            float i_ = gr[j], g_ = gr[128 + j], o_ = gr[256 + j];
            float si = 1.f/(1.f + expf(-i_));
            float c  = si * tanhf(g_);
            float so = 1.f/(1.f + expf(-o_));
            float v = clipf(so * tanhf(c));
            short h, l; split_bf16(v, h, l);
            int d = ((r >> 4)*4 + (j >> 5))*512 + ((j >> 3) & 3)*128 + (r & 15)*8 + (j & 7);
            Lh[d] = h; Ll[d] = l;
        }
    }
    __syncthreads();

    // ---- phase 1: z0 = relu([ue|lstm] @ wc0^T + bc0); wave = 32 rows x 64 cols
    {
        const int tg0 = (wave >> 1) * 4;          // first 16-col tile
        const int wrb = (wave & 1) * 2;           // row-block offset (16-row units)
        f32x4 acc[2][4];
        #pragma unroll
        for (int m = 0; m < 2; ++m)
            #pragma unroll
            for (int t = 0; t < 4; ++t) acc[m][t] = (f32x4){0.f, 0.f, 0.f, 0.f};

        #pragma unroll
        for (int ko = 0; ko < 256; ko += KC){
            const bool lo = (ko < 128);
            const int kk0 = lo ? ko : ko - 128;
            bf16x8 ah[2], al[2];
            #pragma unroll
            for (int m = 0; m < 2; ++m){
                if (lo){
                    long ab = ((((long)((row0 >> 4) + wrb + m)*4 + (kk0 >> 5))*64) + lane)*8;
                    ah[m] = *(const bf16x8*)(ueh + ab);
                    al[m] = *(const bf16x8*)(uel + ab);
                } else {
                    int d = ((wrb + m)*4 + (kk0 >> 5))*512 + lane*8;
                    ah[m] = *(const bf16x8*)&Lh[d];
                    al[m] = *(const bf16x8*)&Ll[d];
                }
            }
            #pragma unroll
            for (int t = 0; t < 4; ++t){
                long wb = ((((long)(tg0 + t)*8 + (ko >> 5))*64) + lane)*8;
                bf16x8 bh = *(const bf16x8*)(wh + wb);
                bf16x8 bl = *(const bf16x8*)(wl + wb);
                #pragma unroll
                for (int m = 0; m < 2; ++m){
                    acc[m][t] = __builtin_amdgcn_mfma_f32_16x16x32_bf16(ah[m], bh, acc[m][t], 0, 0, 0);
                    acc[m][t] = __builtin_amdgcn_mfma_f32_16x16x32_bf16(ah[m], bl, acc[m][t], 0, 0, 0);
                    acc[m][t] = __builtin_amdgcn_mfma_f32_16x16x32_bf16(al[m], bh, acc[m][t], 0, 0, 0);
                }
            }
        }
        #pragma unroll
        for (int m = 0; m < 2; ++m)
            #pragma unroll
            for (int t = 0; t < 4; ++t){
                int gcol = (tg0 + t)*16 + lm;
                float b = bias[gcol];
                #pragma unroll
                for (int r = 0; r < 4; ++r){
                    int rowl = (wave & 1)*32 + m*16 + quad*4 + r;
                    z0L[rowl][gcol] = fmaxf(acc[m][t][r] + b, 0.f);
                }
            }
    }
    __syncthreads();

    // ---- phase 2: z1 = relu(z0 @ wtc1 + bc1); out = z1 @ wc2^T + bc2
    const int c  = tid % CT;
    const int rt = tid / CT;
    float acc2[TM][TN];
    #pragma unroll
    for (int i = 0; i < TM; ++i)
        #pragma unroll
        for (int j = 0; j < TN; ++j) acc2[i][j] = 0.f;

    for (int ko = 0; ko < 128; ko += KC){
        #pragma unroll
        for (int it = 0; it < 2; ++it){
            int idx = it*THREADS + tid;
            int r  = idx >> 3;
            int k4 = idx & 7;
            float4 v = *(const float4*)&z0L[r][ko + k4*4];
            As[k4*4+0][r] = v.x;
            As[k4*4+1][r] = v.y;
            As[k4*4+2][r] = v.z;
            As[k4*4+3][r] = v.w;
        }
        #pragma unroll
        for (int it = 0; it < 2; ++it){
            int idx = it*THREADS + tid;
            int kk = idx / (BN/4);
            int c4 = idx % (BN/4);
            float4 v = *(const float4*)&wt[(long)(ko+kk)*BN + c4*4];
            *(float4*)&Ws[kk][c4*4] = v;
        }
        __syncthreads();
        #pragma unroll
        for (int kk = 0; kk < KC; ++kk){
            float4 wv = *(const float4*)&Ws[kk][c*4];
            float w[TN] = {wv.x, wv.y, wv.z, wv.w};
            float a[TM];
            float4 av = *(const float4*)&As[kk][rt*TM];
            a[0] = av.x; a[1] = av.y; a[2] = av.z; a[3] = av.w;
            #pragma unroll
            for (int i = 0; i < TM; ++i)
                #pragma unroll
                for (int j = 0; j < TN; ++j) acc2[i][j] = fmaf(a[i], w[j], acc2[i][j]);
        }
        __syncthreads();
    }

    #pragma unroll
    for (int i = 0; i < TM; ++i)
        #pragma unroll
        for (int j = 0; j < TN; ++j)
            Zs[rt*TM + i][c*4 + j] = fmaxf(acc2[i][j] + bias1[c*4 + j], 0.f);
    __syncthreads();

    int row = tid & 63;
    int grow = row0 + row;
    if (grow >= M) return;
    #pragma unroll
    for (int jj = 0; jj < 2; ++jj){
        int j = (tid >> 6) + jj*4;
        if (j >= 5) continue;
        float s = bc2[j];
        #pragma unroll 16
        for (int k = 0; k < 64; ++k) s = fmaf(Zs[row][k], Wc[j][k], s);
        out[(long)grow*5 + j] = s;
    }
}

// ----------------------------------------------------------------
extern "C" void kernel_launch(void* const* d_in, const int* in_sizes, int n_in,
                              void* d_out, int out_size, void* d_ws, size_t ws_size,
                              hipStream_t stream){
    const float* x     = (const float*)d_in[0];
    const int*   edge  = (const int*)  d_in[1];
    const int*   uid   = (const int*)  d_in[2];
    const int*   roles = (const int*)  d_in[3];
    const float* w_l0  = (const float*)d_in[4];
    const float* b_l0  = (const float*)d_in[5];
    const float* w_r0  = (const float*)d_in[6];
    const float* w_l1  = (const float*)d_in[7];
    const float* b_l1  = (const float*)d_in[8];
    const float* w_r1  = (const float*)d_in[9];
    const float* w_ih  = (const float*)d_in[10];
    // d_in[11] = w_hh: dead (h0 = 0)
    const float* b_ih  = (const float*)d_in[12];
    const float* b_hh  = (const float*)d_in[13];
    const float* wc0   = (const float*)d_in[14];
    const float* bc0   = (const float*)d_in[15];
    const float* wc1   = (const float*)d_in[16];
    const float* bc1   = (const float*)d_in[17];
    const float* wc2   = (const float*)d_in[18];
    const float* bc2   = (const float*)d_in[19];

    const int N = in_sizes[0] / 128;
    const int E = in_sizes[1] / 2;
    const int B = in_sizes[2];
    const int nbuckets = (N + BNODES - 1) >> BSHIFT;

    char* ws = (char*)d_ws;
    size_t off = 0;
    auto alloc = [&](size_t bytes) -> void* {
        void* p = ws + off; off += (bytes + 255) & ~(size_t)255; return p;
    };
    float* arenaA   = (float*)alloc((size_t)N*128*4);   // mean0h -> mean1h/l -> gates
    float* arenaB   = (float*)alloc((size_t)N*128*4);   // pairs -> user splits
    float* ue       = (float*)alloc((size_t)B*128*4);   // ueh/uel split pair (packed)
    __half* xh      = (__half*)alloc((size_t)N*128*2);
    __half* hh      = (__half*)alloc((size_t)N*128*2);
    // zero-init region (one memset): flag, ucnt, bcnt
    int*   flag     = (int*)  alloc((size_t)N*4);
    int*   ucnt     = (int*)  alloc(256);
    int*   bcnt     = (int*)  alloc(NB_MAX*4);
    char*  zero_end = ws + off;
    int*   row_start= (int*)  alloc((size_t)(N+1)*4);
    int*   boffs    = (int*)  alloc((size_t)(NB_MAX+1)*4);
    int*   bcur    = (int*)  alloc((size_t)NB_MAX*4);
    int*   col_idx  = (int*)  alloc((size_t)E*4);
    int*   ulist    = (int*)  alloc((size_t)B*4);
    __half* wt0f    = (__half*)alloc(128*256*2);
    short* wt1h     = (short*)alloc(128*256*2);
    short* wt1l     = (short*)alloc(128*256*2);
    short* wgh      = (short*)alloc(384*256*2);
    short* wgl      = (short*)alloc(384*256*2);
    short* wc0h     = (short*)alloc(128*256*2);
    short* wc0l     = (short*)alloc(128*256*2);
    float* wtc1     = (float*)alloc(128*64*4);
    float* bsum     = (float*)alloc(384*4);
    float* ohtab    = (float*)alloc(5*384*4);

    // arenaA: mean0h (consumed by gemm32) -> mean1h/mean1l (consumed by gemmM<1>) -> gates
    int2*  pairs  = (int2*)arenaB;               // consumed by fill_bucket2
    __half* mean0h = (__half*)arenaA;
    short* mean1h = (short*)arenaA;              // N*128 shorts (node-indexed, user rows only)
    short* mean1l = (short*)arenaA + (size_t)N*128;
    float* gates  = arenaA;                      // after gemmM<1> consumed mean1
    // arenaB layout after CSR build: user splits
    short* xuh    = (short*)arenaB;
    short* xul    = xuh + (size_t)B*128;
    short* huh    = xul + (size_t)B*128;
    short* hul    = huh + (size_t)B*128;
    // ue region: split pair
    short* ueh    = (short*)ue;
    short* uel    = (short*)ue + (size_t)B*128;

    hipMemsetAsync(flag, 0, (size_t)(zero_end - (char*)flag), stream);

    const int gEC   = (E + ECHUNK - 1)/ECHUNK;
    const long n8   = (long)N*128/8;
    const int nConv = (int)((n8 + 255)/256);
    const int nPrep = (205184 + 255)/256;
    const int nFlag = (B + 255)/256;

    setup_k<<<nConv + nPrep + nFlag + gEC, 256, 0, stream>>>(
        x, xh, n8, nConv,
        w_l0, w_r0, w_l1, w_r1, wc0, wc1, w_ih, b_ih, b_hh,
        wt0f, wt1h, wt1l, wgh, wgl, wc0h, wc0l,
        wtc1, bsum, ohtab, nPrep,
        uid, B, flag, nFlag,
        edge + E, E, nbuckets, bcnt);
    scan_compact<<<1 + (N + 255)/256, 256, 0, stream>>>(bcnt, nbuckets, E, N, boffs, bcur, row_start,
                                                        flag, ulist, ucnt);
    bin_edges_priv<<<gEC, 256, 0, stream>>>(edge, edge + E, E, nbuckets, bcur, pairs);
    fill_bucket2<<<nbuckets, 256, 0, stream>>>(pairs, boffs, row_start, col_idx, N);

    // layer 0: fp16 mean over all nodes (group-per-node), then hh = relu([mean0h|xh] @ wt0^T + b_l0)
    aggregate_h16<<<(N + 15)/16, 256, 0, stream>>>(xh, row_start, col_idx, mean0h, N);
    gemm32_mfma<<<(N + 127)/128, 256, 0, stream>>>(mean0h, xh, wt0f, b_l0, hh, N);

    // layer 1 aggregation (split output) + per-user gather/split (packed), fused in one grid
    const int gAgg = (B + 15)/16;
    const int gUsp = (B*32 + 255)/256;
    aggkh_usplit<<<gAgg + gUsp, 256, 0, stream>>>(hh, xh, row_start, col_idx, ulist, ucnt, uid, B,
                                                  mean1h, mean1l, xuh, xul, huh, hul, gAgg);

    // ue = clip([mean1|hh[uid]] @ wt1^T + b_l1) — packed coalesced loads, 64x128 blocks
    gemmM_mfma<1><<<dim3(B/64, 1), 256, 0, stream>>>(mean1h, mean1l, huh, hul, uid, wt1h, wt1l, b_l1,
                                                     nullptr, nullptr, nullptr, ueh, uel, 128, B);

    // gates (i,g,o via gridDim.y=3) — packed coalesced loads
    gemmM_mfma<2><<<dim3(B/64, 3), 256, 0, stream>>>(ueh, uel, xuh, xul, nullptr, wgh, wgl, bsum,
                                                     ohtab, roles, gates, nullptr, nullptr, 384, B);

    // fused lstm + z0 GEMM + z1 + classifier
    gemmM3_tail<<<B/64, 256, 0, stream>>>(ueh, uel, gates, wc0h, wc0l, bc0,
                                          wtc1, bc1, wc2, bc2, (float*)d_out, B);

    (void)n_in; (void)out_size; (void)ws_size;
}

// Round 12
// 398.337 us; speedup vs baseline: 1.0188x; 1.0188x over previous
//
#include <hip/hip_runtime.h>
#include <hip/hip_fp16.h>
#include <math.h>

#define THREADS 256
#define KC 32
#define BSHIFT 9          // 512 nodes per bucket
#define BNODES (1 << BSHIFT)
#define NB_MAX 256        // max buckets (N<=131072)
#define ECHUNK 4096       // edges per block in binning kernels

__device__ __forceinline__ float clipf(float v){ return fminf(fmaxf(v, -10.f), 10.f); }

typedef __attribute__((ext_vector_type(8))) short bf16x8;
typedef __attribute__((ext_vector_type(8))) _Float16 f16x8;
typedef __attribute__((ext_vector_type(4))) float f32x4;
typedef __attribute__((ext_vector_type(16))) float f32x16;

// split fp32 into bf16 hi + bf16 lo (3-term split-GEMM decomposition)
__device__ __forceinline__ void split_bf16(float f, short& hi, short& lo){
    union { float f; unsigned u; } a; a.f = f;
    unsigned r = (a.u + 0x7FFFu + ((a.u >> 16) & 1u)) & 0xFFFF0000u;
    hi = (short)(r >> 16);
    union { unsigned u; float f; } b; b.u = r;
    float rem = f - b.f;
    union { float f; unsigned u; } c; c.f = rem;
    unsigned r2 = c.u + 0x7FFFu + ((c.u >> 16) & 1u);
    lo = (short)(r2 >> 16);
}

// fragment-linear ("packed") layouts: a wave-load of one MFMA fragment is
// base + lane*16B, fully coalesced. Pure storage permutation (same values
// land in the same lanes -> bitwise-identical MFMA inputs).
// W: [ncols][256] -> tile t=n/16, kb=k/32, lane=((k>>3)&3)*16+(n&15), j=k&7
__device__ __forceinline__ long wpk(int n, int k){
    return ((((long)(n >> 4)*8 + (k >> 5))*64) + ((k >> 3) & 3)*16 + (n & 15))*8 + (k & 7);
}
// A: [B][128] -> rb=r/16, kb=k/32 (k in [0,128)), lane=((k>>3)&3)*16+(r&15), j=k&7
__device__ __forceinline__ long apk(int r, int k){
    return ((((long)(r >> 4)*4 + (k >> 5))*64) + ((k >> 3) & 3)*16 + (r & 15))*8 + (k & 7);
}

// ---------------------------------------------------------------- fused setup:
__global__ __launch_bounds__(256) void setup_k(
        const float* __restrict__ x, __half* __restrict__ xh, long n8, int nConv,
        const float* __restrict__ w_l0, const float* __restrict__ w_r0,
        const float* __restrict__ w_l1, const float* __restrict__ w_r1,
        const float* __restrict__ wc0,  const float* __restrict__ wc1,
        const float* __restrict__ w_ih, const float* __restrict__ b_ih, const float* __restrict__ b_hh,
        __half* __restrict__ wt0f,
        short* __restrict__ wt1h, short* __restrict__ wt1l,
        short* __restrict__ wgh,  short* __restrict__ wgl,
        short* __restrict__ wc0h, short* __restrict__ wc0l,
        float* __restrict__ wtc1, float* __restrict__ bsum, float* __restrict__ ohtab, int nPrep,
        const int* __restrict__ uid, int B, int* __restrict__ flag, int nFlag,
        const int* __restrict__ dstv, int E, int nbuckets, int* __restrict__ bcnt){
    __shared__ int hsh[NB_MAX];
    int b = blockIdx.x;
    if (b < nConv){
        long t = (long)b*256 + threadIdx.x;
        if (t >= n8) return;
        long i = t*8;
        float4 a = *(const float4*)(x + i);
        float4 bb = *(const float4*)(x + i + 4);
        union { __half2 h[4]; float4 f; } u;
        u.h[0] = __floats2half2_rn(a.x, a.y);
        u.h[1] = __floats2half2_rn(a.z, a.w);
        u.h[2] = __floats2half2_rn(bb.x, bb.y);
        u.h[3] = __floats2half2_rn(bb.z, bb.w);
        *(float4*)(xh + i) = u.f;
    } else if (b < nConv + nPrep){
        int idx = (b - nConv)*256 + threadIdx.x;
        if (idx < 32768){
            int n = idx >> 8, k = idx & 255;
            float f = (k < 128) ? w_l0[n*128 + k] : w_r0[n*128 + (k - 128)];
            wt0f[idx] = __float2half(f);
        } else if (idx < 65536){
            int i = idx - 32768;
            int n = i >> 8, k = i & 255;
            float f = (k < 128) ? w_l1[n*128 + k] : w_r1[n*128 + (k - 128)];
            short h, l; split_bf16(f, h, l);
            long d = wpk(n, k);
            wt1h[d] = h; wt1l[d] = l;
        } else if (idx < 163840){
            int i = idx - 65536;
            int n = i >> 8, k = i & 255;       // n in [0,384)
            int j = n + ((n >= 128) ? 128 : 0);
            float f = w_ih[j*261 + k];
            short h, l; split_bf16(f, h, l);
            long d = wpk(n, k);
            wgh[d] = h; wgl[d] = l;
        } else if (idx < 196608){
            int i = idx - 163840;
            int n = i >> 8, k = i & 255;
            float f = wc0[i];                  // [128][256] already [n][k]
            short h, l; split_bf16(f, h, l);
            long d = wpk(n, k);
            wc0h[d] = h; wc0l[d] = l;
        } else if (idx < 204800){
            int i = idx - 196608;
            int j = i >> 7, k = i & 127;
            wtc1[k*64 + j] = wc1[j*128 + k];
        } else if (idx < 205184){
            int jj = idx - 204800;
            int j = jj + ((jj >= 128) ? 128 : 0);
            bsum[jj] = b_ih[j] + b_hh[j];
            for (int r = 0; r < 5; ++r) ohtab[r*384 + jj] = w_ih[j*261 + 256 + r];
        }
    } else if (b < nConv + nPrep + nFlag){
        int i = (b - nConv - nPrep)*256 + threadIdx.x;
        if (i < B) flag[uid[i]] = 1;
    } else {
        int lb = b - nConv - nPrep - nFlag;
        int b0 = lb * ECHUNK;
        int b1 = min(b0 + ECHUNK, E);
        for (int i = threadIdx.x; i < nbuckets; i += 256) hsh[i] = 0;
        __syncthreads();
        for (int i = b0 + threadIdx.x; i < b1; i += 256)
            atomicAdd(&hsh[dstv[i] >> BSHIFT], 1);
        __syncthreads();
        for (int i = threadIdx.x; i < nbuckets; i += 256){
            int c = hsh[i];
            if (c) atomicAdd(&bcnt[i], c);
        }
    }
}

// ---------------------------------------------------------------- CSR build (bucket-first)
// block 0: bucket prefix scan; blocks 1..: compact user flags -> ulist
__global__ __launch_bounds__(256) void scan_compact(const int* __restrict__ bcnt, int nb, int E, int N,
                                                    int* __restrict__ boffs, int* __restrict__ bcur, int* __restrict__ row_start,
                                                    const int* __restrict__ flag, int* __restrict__ list, int* __restrict__ cnt){
    if (blockIdx.x == 0){
        __shared__ int sh[256];
        int t = threadIdx.x;
        int v = (t < nb) ? bcnt[t] : 0;
        sh[t] = v; __syncthreads();
        for (int off = 1; off < 256; off <<= 1){
            int u = (t >= off) ? sh[t-off] : 0;
            __syncthreads();
            sh[t] += u;
            __syncthreads();
        }
        int ex = sh[t] - v;
        if (t < nb){ boffs[t] = ex; bcur[t] = ex; }
        if (t == 0){ boffs[nb] = E; row_start[N] = E; }
    } else {
        int i = (blockIdx.x - 1)*256 + threadIdx.x;
        if (i < N && flag[i]){ int p = atomicAdd(cnt, 1); list[p] = i; }
    }
}

__global__ __launch_bounds__(256) void bin_edges_priv(const int* __restrict__ srcv, const int* __restrict__ dstv, int E,
                                                      int nbuckets, int* __restrict__ bcur, int2* __restrict__ pairs){
    __shared__ int cnt[NB_MAX];
    __shared__ int base[NB_MAX];
    int b0 = blockIdx.x * ECHUNK;
    int b1 = min(b0 + ECHUNK, E);
    for (int i = threadIdx.x; i < nbuckets; i += 256) cnt[i] = 0;
    __syncthreads();
    for (int i = b0 + threadIdx.x; i < b1; i += 256)
        atomicAdd(&cnt[dstv[i] >> BSHIFT], 1);
    __syncthreads();
    for (int i = threadIdx.x; i < nbuckets; i += 256){
        int c = cnt[i];
        base[i] = c ? atomicAdd(&bcur[i], c) : 0;
    }
    __syncthreads();
    for (int i = threadIdx.x; i < nbuckets; i += 256) cnt[i] = 0;
    __syncthreads();
    for (int i = b0 + threadIdx.x; i < b1; i += 256){
        int d = dstv[i];
        int bk = d >> BSHIFT;
        int loc = atomicAdd(&cnt[bk], 1);
        pairs[base[bk] + loc] = make_int2(d, srcv[i]);
    }
}

__global__ __launch_bounds__(256) void fill_bucket2(const int2* __restrict__ pairs, const int* __restrict__ boffs,
                                                    int* __restrict__ row_start, int* __restrict__ col_idx, int N){
    __shared__ int cur[BNODES];
    __shared__ int sh[256];
    int b  = blockIdx.x;
    int n0 = b << BSHIFT;
    int nn = min(BNODES, N - n0);
    int s = boffs[b], e = boffs[b+1];
    int t = threadIdx.x;
    cur[2*t]   = 0;
    cur[2*t+1] = 0;
    __syncthreads();
    for (int i = s + t; i < e; i += 256)
        atomicAdd(&cur[pairs[i].x - n0], 1);
    __syncthreads();
    int c0 = cur[2*t], c1 = cur[2*t+1];
    int s2 = c0 + c1;
    sh[t] = s2; __syncthreads();
    for (int off = 1; off < 256; off <<= 1){
        int u = (t >= off) ? sh[t-off] : 0;
        __syncthreads();
        sh[t] += u;
        __syncthreads();
    }
    int ex = sh[t] - s2;
    __syncthreads();
    cur[2*t]   = s + ex;
    cur[2*t+1] = s + ex + c0;
    __syncthreads();
    for (int i = t; i < nn; i += 256) row_start[n0 + i] = cur[i];
    __syncthreads();
    for (int i = s + t; i < e; i += 256){
        int2 p = pairs[i];
        int loc = atomicAdd(&cur[p.x - n0], 1);
        col_idx[loc] = p.y;
    }
}

// ---------------------------------------------------------------- fp16 mean aggregation (fp32 accum)
__device__ __forceinline__ void accumh(float4& a0, float4& a1, float4 v){
    const __half2* h = (const __half2*)&v;
    float2 f0 = __half22float2(h[0]);
    float2 f1 = __half22float2(h[1]);
    float2 f2 = __half22float2(h[2]);
    float2 f3 = __half22float2(h[3]);
    a0.x += f0.x; a0.y += f0.y; a0.z += f1.x; a0.w += f1.y;
    a1.x += f2.x; a1.y += f2.y; a1.z += f3.x; a1.w += f3.y;
}

// group-per-node aggregation body: one 16-lane group owns one node.
// Lane sl owns features [sl*8, sl*8+8). OM=0: fp16 row out; OM=1: split bf16 out.
template<int OM>
__device__ __forceinline__ void agg_group(const __half* __restrict__ feat, const int* __restrict__ row_start,
                                          const int* __restrict__ col_idx, void* __restrict__ o1, void* __restrict__ o2,
                                          int node, int sl){
    int s = row_start[node], e = row_start[node+1];
    const float4* f16 = (const float4*)feat;
    float4 a0 = make_float4(0.f,0.f,0.f,0.f);
    float4 a1 = make_float4(0.f,0.f,0.f,0.f);
    int i = s;
    for (; i + 7 < e; i += 8){                 // 8 loads in flight
        int c0 = col_idx[i+0];
        int c1 = col_idx[i+1];
        int c2 = col_idx[i+2];
        int c3 = col_idx[i+3];
        int c4 = col_idx[i+4];
        int c5 = col_idx[i+5];
        int c6 = col_idx[i+6];
        int c7 = col_idx[i+7];
        float4 v0 = f16[(long)c0*16 + sl];
        float4 v1 = f16[(long)c1*16 + sl];
        float4 v2 = f16[(long)c2*16 + sl];
        float4 v3 = f16[(long)c3*16 + sl];
        float4 v4 = f16[(long)c4*16 + sl];
        float4 v5 = f16[(long)c5*16 + sl];
        float4 v6 = f16[(long)c6*16 + sl];
        float4 v7 = f16[(long)c7*16 + sl];
        accumh(a0, a1, v0);
        accumh(a0, a1, v1);
        accumh(a0, a1, v2);
        accumh(a0, a1, v3);
        accumh(a0, a1, v4);
        accumh(a0, a1, v5);
        accumh(a0, a1, v6);
        accumh(a0, a1, v7);
    }
    if (i + 3 < e){                            // 4-deep tail
        int c0 = col_idx[i+0];
        int c1 = col_idx[i+1];
        int c2 = col_idx[i+2];
        int c3 = col_idx[i+3];
        float4 v0 = f16[(long)c0*16 + sl];
        float4 v1 = f16[(long)c1*16 + sl];
        float4 v2 = f16[(long)c2*16 + sl];
        float4 v3 = f16[(long)c3*16 + sl];
        accumh(a0, a1, v0);
        accumh(a0, a1, v1);
        accumh(a0, a1, v2);
        accumh(a0, a1, v3);
        i += 4;
    }
    if (i + 1 < e){                            // 2-deep tail
        int c0 = col_idx[i+0];
        int c1 = col_idx[i+1];
        float4 v0 = f16[(long)c0*16 + sl];
        float4 v1 = f16[(long)c1*16 + sl];
        accumh(a0, a1, v0);
        accumh(a0, a1, v1);
        i += 2;
    }
    if (i < e){                                // final single
        float4 v0 = f16[(long)col_idx[i]*16 + sl];
        accumh(a0, a1, v0);
    }
    float inv = 1.f / fmaxf((float)(e - s), 1.f);
    a0.x *= inv; a0.y *= inv; a0.z *= inv; a0.w *= inv;
    a1.x *= inv; a1.y *= inv; a1.z *= inv; a1.w *= inv;
    if constexpr (OM == 0){
        union { __half2 h[4]; int4 v; } u;
        u.h[0] = __floats2half2_rn(a0.x, a0.y);
        u.h[1] = __floats2half2_rn(a0.z, a0.w);
        u.h[2] = __floats2half2_rn(a1.x, a1.y);
        u.h[3] = __floats2half2_rn(a1.z, a1.w);
        *(int4*)((__half*)o1 + (long)node*128 + sl*8) = u.v;
    } else {
        float vals[8] = {a0.x, a0.y, a0.z, a0.w, a1.x, a1.y, a1.z, a1.w};
        union { short s[8]; int4 v; } uh, ul;
        #pragma unroll
        for (int j = 0; j < 8; ++j) split_bf16(vals[j], uh.s[j], ul.s[j]);
        *(int4*)((short*)o1 + (long)node*128 + sl*8) = uh.v;
        *(int4*)((short*)o2 + (long)node*128 + sl*8) = ul.v;
    }
}

__global__ __launch_bounds__(256) void aggregate_h16(const __half* __restrict__ feat, const int* __restrict__ row_start,
                                                     const int* __restrict__ col_idx,
                                                     __half* __restrict__ outmean, int N){
    int node = (blockIdx.x*256 + threadIdx.x) >> 4;   // one 16-lane group per node
    if (node >= N) return;
    agg_group<0>(feat, row_start, col_idx, outmean, nullptr, node, threadIdx.x & 15);
}

// fused: user-node aggregation (split output, mean1 row-major node-indexed)
// + per-user gather/split of xh/hh rows (PACKED batch-row layout)
__global__ __launch_bounds__(256) void aggkh_usplit(const __half* __restrict__ hh, const __half* __restrict__ xh,
                                                    const int* __restrict__ row_start, const int* __restrict__ col_idx,
                                                    const int* __restrict__ list, const int* __restrict__ cnt,
                                                    const int* __restrict__ uid, int B,
                                                    short* __restrict__ mean1h, short* __restrict__ mean1l,
                                                    short* __restrict__ xuh, short* __restrict__ xul,
                                                    short* __restrict__ huh, short* __restrict__ hul, int gAgg){
    int b = blockIdx.x;
    if (b < gAgg){
        int w = (b*256 + threadIdx.x) >> 4;
        if (w >= *cnt) return;
        agg_group<1>(hh, row_start, col_idx, mean1h, mean1l, list[w], threadIdx.x & 15);
    } else {
        int t = (b - gAgg)*256 + threadIdx.x;
        if (t >= B*32) return;
        int r = t >> 5, k4 = t & 31;
        long so = (long)uid[r]*128 + k4*4;
        long dofs = apk(r, k4*4);   // int2 spans j..j+3 within one packed octet
        union { int2 p; __half h[4]; } ux, uh;
        ux.p = *(const int2*)(xh + so);
        uh.p = *(const int2*)(hh + so);
        union { short s[4]; int2 p; } xa, xb, ha, hb;
        #pragma unroll
        for (int j = 0; j < 4; ++j){
            float vx = clipf(__half2float(ux.h[j]));
            split_bf16(vx, xa.s[j], xb.s[j]);
            float vh = __half2float(uh.h[j]);
            split_bf16(vh, ha.s[j], hb.s[j]);
        }
        *(int2*)(xuh + dofs) = xa.p;
        *(int2*)(xul + dofs) = xb.p;
        *(int2*)(huh + dofs) = ha.p;
        *(int2*)(hul + dofs) = hb.p;
    }
}

// ---------------------------------------------------------------- layer-0 GEMM via f16 32x32x16 MFMA (single-term)
// hh = relu([mean0h|xh] @ wt0^T + b_l0); all A inputs already fp16 -> raw int4 staging.
__global__ __launch_bounds__(256) void gemm32_mfma(const __half* __restrict__ mean0h, const __half* __restrict__ xh,
                                                   const __half* __restrict__ wf,
                                                   const float* __restrict__ bias,
                                                   __half* __restrict__ outh, int M){
    __shared__ __align__(16) _Float16 As[8*64*8];   // 8 regions x 64 lanes x 8 halfs = 8 KB
    __shared__ __align__(16) _Float16 Ws[8*64*8];

    const int tid  = threadIdx.x;
    const int row0 = blockIdx.x * 128;
    const int wave = tid >> 6, lane = tid & 63;
    const int wr = wave >> 1, wc = wave & 1;
    const int c32 = lane & 31, gg = lane >> 5;

    f32x16 acc[2][2];
    #pragma unroll
    for (int rm = 0; rm < 2; ++rm)
        #pragma unroll
        for (int cn = 0; cn < 2; ++cn)
            #pragma unroll
            for (int r = 0; r < 16; ++r) acc[rm][cn][r] = 0.f;

    for (int ko = 0; ko < 256; ko += KC){
        // stage A (128 rows x 32 k) — pure int4 copies
        #pragma unroll
        for (int it = 0; it < 2; ++it){
            int cid = it*256 + tid;
            int row = cid >> 2, s = (cid >> 1) & 1, g = cid & 1;
            int grow = row0 + row; if (grow >= M) grow = M - 1;
            int k = ko + s*16 + g*8;
            int slot = ((s*4 + (row >> 5))*64 + g*32 + (row & 31)) * 8;
            const __half* p = (k < 128) ? (mean0h + (long)grow*128 + k) : (xh + (long)grow*128 + (k - 128));
            *(int4*)&As[slot] = *(const int4*)p;
        }
        // stage W (128 cols x 32 k), fp16 weights
        #pragma unroll
        for (int it = 0; it < 2; ++it){
            int cid = it*256 + tid;
            int n = cid >> 2, s = (cid >> 1) & 1, g = cid & 1;
            int k = ko + s*16 + g*8;
            int4 vh = *(const int4*)(wf + (long)n*256 + k);
            int slot = ((s*4 + (n >> 5))*64 + g*32 + (n & 31)) * 8;
            *(int4*)&Ws[slot] = vh;
        }
        __syncthreads();

        #pragma unroll
        for (int s = 0; s < 2; ++s){
            f16x8 ah[2], bh[2];
            #pragma unroll
            for (int rm = 0; rm < 2; ++rm){
                int reg = (s*4 + 2*wr + rm)*64 + lane;
                ah[rm] = *(const f16x8*)&As[reg*8];
            }
            #pragma unroll
            for (int cn = 0; cn < 2; ++cn){
                int reg = (s*4 + 2*wc + cn)*64 + lane;
                bh[cn] = *(const f16x8*)&Ws[reg*8];
            }
            #pragma unroll
            for (int rm = 0; rm < 2; ++rm)
                #pragma unroll
                for (int cn = 0; cn < 2; ++cn)
                    acc[rm][cn] = __builtin_amdgcn_mfma_f32_32x32x16_f16(ah[rm], bh[cn], acc[rm][cn], 0, 0, 0);
        }
        __syncthreads();
    }

    // epilogue: C/D row = (reg&3) + 8*(reg>>2) + 4*(lane>>5), col = lane&31 (m74/m101)
    #pragma unroll
    for (int rm = 0; rm < 2; ++rm)
        #pragma unroll
        for (int cn = 0; cn < 2; ++cn){
            int col = (2*wc + cn)*32 + c32;
            float b = bias[col];
            #pragma unroll
            for (int r = 0; r < 16; ++r){
                int row = row0 + (2*wr + rm)*32 + (r & 3) + 8*(r >> 2) + 4*gg;
                if (row < M)
                    outh[(long)row*128 + col] = __float2half(fmaxf(acc[rm][cn][r] + b, 0.f));
            }
        }
}

// ---------------------------------------------------------------- B-row GEMMs: no LDS/barriers, PACKED coalesced loads
// Block = 4 waves = 64 rows x 128 cols. Wave = 32 rows x 64 cols (2 m-tiles x 4 t-tiles).
// MODE 1: ue = clip([mean1|hh[uid]] @ wt1^T + b_l1)   A0 node-gathered (scattered); OUT packed split bf16
// MODE 2: gates_cg = [ue|xu] @ wg_cg^T + bsum + ohtab cg = blockIdx.y; OUT fp32 [B][384]
// MODE 3: z0 = relu([ue|lstm] @ wc0^T + bc0)          OUT fp32 [B][128]
template<int MODE>
__global__ __launch_bounds__(256) void gemmM_mfma(const short* __restrict__ aH0, const short* __restrict__ aL0,
                                                  const short* __restrict__ aH1, const short* __restrict__ aL1,
                                                  const int* __restrict__ g,
                                                  const short* __restrict__ wh, const short* __restrict__ wl,
                                                  const float* __restrict__ bias, const float* __restrict__ ohtab,
                                                  const int* __restrict__ roles,
                                                  float* __restrict__ out, short* __restrict__ outH, short* __restrict__ outL,
                                                  int ncolsOut, int M){
    const int lane = threadIdx.x & 63;
    const int wave = threadIdx.x >> 6;
    const int lm = lane & 15, quad = lane >> 4;
    const int row0 = blockIdx.x * 64 + (wave & 1) * 32;   // wave's 32-row span
    const int tg0  = blockIdx.y * 8 + (wave >> 1) * 4;    // wave's first 16-col tile index

    long r0[2];
    if constexpr (MODE == 1){
        #pragma unroll
        for (int m = 0; m < 2; ++m){
            int ar = row0 + m*16 + lm; if (ar >= M) ar = M - 1;
            r0[m] = (long)g[ar];
        }
    }

    f32x4 acc[2][4];
    #pragma unroll
    for (int m = 0; m < 2; ++m)
        #pragma unroll
        for (int t = 0; t < 4; ++t) acc[m][t] = (f32x4){0.f, 0.f, 0.f, 0.f};

    #pragma unroll
    for (int ko = 0; ko < 256; ko += KC){
        const bool lo = (ko < 128);
        const int kk0 = lo ? ko : ko - 128;
        bf16x8 ah[2], al[2];
        #pragma unroll
        for (int m = 0; m < 2; ++m){
            if (MODE == 1 && lo){
                // mean1: node-indexed row-major, gathered (scattered load)
                ah[m] = *(const bf16x8*)(aH0 + r0[m]*128 + kk0 + quad*8);
                al[m] = *(const bf16x8*)(aL0 + r0[m]*128 + kk0 + quad*8);
            } else {
                const short* sH = lo ? aH0 : aH1;
                const short* sL = lo ? aL0 : aL1;
                long ab = ((((long)((row0 >> 4) + m)*4 + (kk0 >> 5))*64) + lane)*8;
                ah[m] = *(const bf16x8*)(sH + ab);
                al[m] = *(const bf16x8*)(sL + ab);
            }
        }
        #pragma unroll
        for (int t = 0; t < 4; ++t){
            long wb = ((((long)(tg0 + t)*8 + (ko >> 5))*64) + lane)*8;
            bf16x8 bh = *(const bf16x8*)(wh + wb);
            bf16x8 bl = *(const bf16x8*)(wl + wb);
            #pragma unroll
            for (int m = 0; m < 2; ++m){
                acc[m][t] = __builtin_amdgcn_mfma_f32_16x16x32_bf16(ah[m], bh, acc[m][t], 0, 0, 0);
                acc[m][t] = __builtin_amdgcn_mfma_f32_16x16x32_bf16(ah[m], bl, acc[m][t], 0, 0, 0);
                acc[m][t] = __builtin_amdgcn_mfma_f32_16x16x32_bf16(al[m], bh, acc[m][t], 0, 0, 0);
            }
        }
    }

    #pragma unroll
    for (int m = 0; m < 2; ++m){
        #pragma unroll
        for (int t = 0; t < 4; ++t){
            int gcol = (tg0 + t)*16 + lm;
            float b = bias[gcol];
            #pragma unroll
            for (int r = 0; r < 4; ++r){
                int row = row0 + m*16 + quad*4 + r;
                if (row >= M) continue;
                float v = acc[m][t][r] + b;
                if constexpr (MODE == 1){
                    v = clipf(v);
                    short h, l; split_bf16(v, h, l);
                    long d = apk(row, gcol);
                    outH[d] = h;
                    outL[d] = l;
                } else if constexpr (MODE == 2){
                    out[(long)row*ncolsOut + gcol] = v + ohtab[roles[row]*384 + gcol];
                } else {
                    out[(long)row*ncolsOut + gcol] = fmaxf(v, 0.f);
                }
            }
        }
    }
}

// ---------------------------------------------------------------- LSTM activation (f-gate dead, c0=0) + packed split
__global__ __launch_bounds__(256) void lstm_act(const float* __restrict__ gates,
                                                short* __restrict__ lstmh, short* __restrict__ lstml, int B){
    int idx = blockIdx.x*256 + threadIdx.x;
    if (idx >= B*128) return;
    int b = idx >> 7, j = idx & 127;
    const float* gr = gates + (long)b*384;
    float i_ = gr[j], g_ = gr[128 + j], o_ = gr[256 + j];
    float si = 1.f/(1.f + expf(-i_));
    float c  = si * tanhf(g_);
    float so = 1.f/(1.f + expf(-o_));
    float v = clipf(so * tanhf(c));
    short h, l; split_bf16(v, h, l);
    long d = apk(b, j);
    lstmh[d] = h;
    lstml[d] = l;
}

// ---------------------------------------------------------------- fused tail: z1 = relu(z0 @ wtc1 + bc1); out = z1 @ wc2^T + bc2
__global__ __launch_bounds__(THREADS) void tail_k(const float* __restrict__ a0, const float* __restrict__ wt,
                                                  const float* __restrict__ bias,
                                                  const float* __restrict__ wc2, const float* __restrict__ bc2,
                                                  float* __restrict__ out, int M){
    constexpr int BM = 64;
    constexpr int BN = 64;
    constexpr int TN = 4;
    constexpr int CT = BN / TN;          // 16
    constexpr int RT = THREADS / CT;     // 16
    constexpr int TM = BM / RT;          // 4
    constexpr int KTOT = 128;
    constexpr int AST = BM + 4;

    __shared__ __align__(16) float As[KC][AST];
    __shared__ __align__(16) float Ws[KC][BN];
    __shared__ float Zs[BM][BN + 1];     // z1 tile, pad 65 -> conflict-free column reads
    __shared__ float Wc[5][64];

    const int tid  = threadIdx.x;
    const int row0 = blockIdx.x * BM;
    const int c  = tid % CT;
    const int rt = tid / CT;

    for (int i = tid; i < 320; i += THREADS) Wc[i >> 6][i & 63] = wc2[i];   // all 5 rows (bugfix r13)

    float acc[TM][TN];
    #pragma unroll
    for (int i = 0; i < TM; ++i)
        #pragma unroll
        for (int j = 0; j < TN; ++j) acc[i][j] = 0.f;

    for (int ko = 0; ko < KTOT; ko += KC){
        #pragma unroll
        for (int it = 0; it < 2; ++it){
            int idx = it*THREADS + tid;
            int r  = idx >> 3;
            int k4 = idx & 7;
            int grow = row0 + r; if (grow >= M) grow = M - 1;
            float4 v = *(const float4*)(a0 + (long)grow*128 + ko + k4*4);
            As[k4*4+0][r] = v.x;
            As[k4*4+1][r] = v.y;
            As[k4*4+2][r] = v.z;
            As[k4*4+3][r] = v.w;
        }
        #pragma unroll
        for (int it = 0; it < 2; ++it){
            int idx = it*THREADS + tid;
            int kk = idx / (BN/4);
            int c4 = idx % (BN/4);
            float4 v = *(const float4*)&wt[(long)(ko+kk)*BN + c4*4];
            *(float4*)&Ws[kk][c4*4] = v;
        }
        __syncthreads();
        #pragma unroll
        for (int kk = 0; kk < KC; ++kk){
            float4 wv = *(const float4*)&Ws[kk][c*4];
            float w[TN] = {wv.x, wv.y, wv.z, wv.w};
            float a[TM];
            float4 av = *(const float4*)&As[kk][rt*TM];
            a[0] = av.x; a[1] = av.y; a[2] = av.z; a[3] = av.w;
            #pragma unroll
            for (int i = 0; i < TM; ++i)
                #pragma unroll
                for (int j = 0; j < TN; ++j) acc[i][j] = fmaf(a[i], w[j], acc[i][j]);
        }
        __syncthreads();
    }

    // z1 tile -> LDS
    #pragma unroll
    for (int i = 0; i < TM; ++i)
        #pragma unroll
        for (int j = 0; j < TN; ++j)
            Zs[rt*TM + i][c*4 + j] = fmaxf(acc[i][j] + bias[c*4 + j], 0.f);
    __syncthreads();

    // classifier: row = tid&63, j in {tid>>6, tid>>6 + 4} (j<5)
    int row = tid & 63;
    int grow = row0 + row;
    if (grow >= M) return;
    #pragma unroll
    for (int jj = 0; jj < 2; ++jj){
        int j = (tid >> 6) + jj*4;
        if (j >= 5) continue;
        float s = bc2[j];
        #pragma unroll 16
        for (int k = 0; k < 64; ++k) s = fmaf(Zs[row][k], Wc[j][k], s);
        out[(long)grow*5 + j] = s;
    }
}

// ----------------------------------------------------------------
extern "C" void kernel_launch(void* const* d_in, const int* in_sizes, int n_in,
                              void* d_out, int out_size, void* d_ws, size_t ws_size,
                              hipStream_t stream){
    const float* x     = (const float*)d_in[0];
    const int*   edge  = (const int*)  d_in[1];
    const int*   uid   = (const int*)  d_in[2];
    const int*   roles = (const int*)  d_in[3];
    const float* w_l0  = (const float*)d_in[4];
    const float* b_l0  = (const float*)d_in[5];
    const float* w_r0  = (const float*)d_in[6];
    const float* w_l1  = (const float*)d_in[7];
    const float* b_l1  = (const float*)d_in[8];
    const float* w_r1  = (const float*)d_in[9];
    const float* w_ih  = (const float*)d_in[10];
    // d_in[11] = w_hh: dead (h0 = 0)
    const float* b_ih  = (const float*)d_in[12];
    const float* b_hh  = (const float*)d_in[13];
    const float* wc0   = (const float*)d_in[14];
    const float* bc0   = (const float*)d_in[15];
    const float* wc1   = (const float*)d_in[16];
    const float* bc1   = (const float*)d_in[17];
    const float* wc2   = (const float*)d_in[18];
    const float* bc2   = (const float*)d_in[19];

    const int N = in_sizes[0] / 128;
    const int E = in_sizes[1] / 2;
    const int B = in_sizes[2];
    const int nbuckets = (N + BNODES - 1) >> BSHIFT;

    char* ws = (char*)d_ws;
    size_t off = 0;
    auto alloc = [&](size_t bytes) -> void* {
        void* p = ws + off; off += (bytes + 255) & ~(size_t)255; return p;
    };
    float* arenaA   = (float*)alloc((size_t)N*128*4);   // mean0h -> mean1h/l -> gates
    float* arenaB   = (float*)alloc((size_t)N*128*4);   // pairs -> lstm split/z0/user splits
    float* ue       = (float*)alloc((size_t)B*128*4);   // ueh/uel split pair (packed)
    __half* xh      = (__half*)alloc((size_t)N*128*2);
    __half* hh      = (__half*)alloc((size_t)N*128*2);
    // zero-init region (one memset): flag, ucnt, bcnt
    int*   flag     = (int*)  alloc((size_t)N*4);
    int*   ucnt     = (int*)  alloc(256);
    int*   bcnt     = (int*)  alloc(NB_MAX*4);
    char*  zero_end = ws + off;
    int*   row_start= (int*)  alloc((size_t)(N+1)*4);
    int*   boffs    = (int*)  alloc((size_t)(NB_MAX+1)*4);
    int*   bcur    = (int*)  alloc((size_t)NB_MAX*4);
    int*   col_idx  = (int*)  alloc((size_t)E*4);
    int*   ulist    = (int*)  alloc((size_t)B*4);
    __half* wt0f    = (__half*)alloc(128*256*2);
    short* wt1h     = (short*)alloc(128*256*2);
    short* wt1l     = (short*)alloc(128*256*2);
    short* wgh      = (short*)alloc(384*256*2);
    short* wgl      = (short*)alloc(384*256*2);
    short* wc0h     = (short*)alloc(128*256*2);
    short* wc0l     = (short*)alloc(128*256*2);
    float* wtc1     = (float*)alloc(128*64*4);
    float* bsum     = (float*)alloc(384*4);
    float* ohtab    = (float*)alloc(5*384*4);

    // arenaA: mean0h (consumed by gemm32) -> mean1h/mean1l (consumed by gemmM<1>) -> gates
    int2*  pairs  = (int2*)arenaB;               // consumed by fill_bucket2
    __half* mean0h = (__half*)arenaA;
    short* mean1h = (short*)arenaA;              // N*128 shorts (node-indexed, user rows only)
    short* mean1l = (short*)arenaA + (size_t)N*128;
    float* gates  = arenaA;                      // after gemmM<1> consumed mean1
    // arenaB layout after CSR build: [0,4M) lstmh [4M,8M) lstml [8M,16M) z0 [16M,32M) user splits
    short* lstmh  = (short*)arenaB;
    short* lstml  = (short*)arenaB + (size_t)B*128;
    float* z0     = (float*)((char*)arenaB + (size_t)B*128*4);
    short* xuh    = (short*)((char*)arenaB + (size_t)B*128*8);
    short* xul    = xuh + (size_t)B*128;
    short* huh    = xul + (size_t)B*128;
    short* hul    = huh + (size_t)B*128;
    // ue region: split pair
    short* ueh    = (short*)ue;
    short* uel    = (short*)ue + (size_t)B*128;

    hipMemsetAsync(flag, 0, (size_t)(zero_end - (char*)flag), stream);

    const int gEC   = (E + ECHUNK - 1)/ECHUNK;
    const long n8   = (long)N*128/8;
    const int nConv = (int)((n8 + 255)/256);
    const int nPrep = (205184 + 255)/256;
    const int nFlag = (B + 255)/256;

    setup_k<<<nConv + nPrep + nFlag + gEC, 256, 0, stream>>>(
        x, xh, n8, nConv,
        w_l0, w_r0, w_l1, w_r1, wc0, wc1, w_ih, b_ih, b_hh,
        wt0f, wt1h, wt1l, wgh, wgl, wc0h, wc0l,
        wtc1, bsum, ohtab, nPrep,
        uid, B, flag, nFlag,
        edge + E, E, nbuckets, bcnt);
    scan_compact<<<1 + (N + 255)/256, 256, 0, stream>>>(bcnt, nbuckets, E, N, boffs, bcur, row_start,
                                                        flag, ulist, ucnt);
    bin_edges_priv<<<gEC, 256, 0, stream>>>(edge, edge + E, E, nbuckets, bcur, pairs);
    fill_bucket2<<<nbuckets, 256, 0, stream>>>(pairs, boffs, row_start, col_idx, N);

    // layer 0: fp16 mean over all nodes (group-per-node), then hh = relu([mean0h|xh] @ wt0^T + b_l0)
    aggregate_h16<<<(N + 15)/16, 256, 0, stream>>>(xh, row_start, col_idx, mean0h, N);
    gemm32_mfma<<<(N + 127)/128, 256, 0, stream>>>(mean0h, xh, wt0f, b_l0, hh, N);

    // layer 1 aggregation (split output) + per-user gather/split (packed), fused in one grid
    const int gAgg = (B + 15)/16;
    const int gUsp = (B*32 + 255)/256;
    aggkh_usplit<<<gAgg + gUsp, 256, 0, stream>>>(hh, xh, row_start, col_idx, ulist, ucnt, uid, B,
                                                  mean1h, mean1l, xuh, xul, huh, hul, gAgg);

    // ue = clip([mean1|hh[uid]] @ wt1^T + b_l1) — packed coalesced loads, 64x128 blocks
    gemmM_mfma<1><<<dim3(B/64, 1), 256, 0, stream>>>(mean1h, mean1l, huh, hul, uid, wt1h, wt1l, b_l1,
                                                     nullptr, nullptr, nullptr, ueh, uel, 128, B);

    // gates (i,g,o via gridDim.y=3) — packed coalesced loads
    gemmM_mfma<2><<<dim3(B/64, 3), 256, 0, stream>>>(ueh, uel, xuh, xul, nullptr, wgh, wgl, bsum,
                                                     ohtab, roles, gates, nullptr, nullptr, 384, B);
    lstm_act<<<(B*128 + 255)/256, 256, 0, stream>>>(gates, lstmh, lstml, B);

    // z0 = relu([ue|lstm] @ wc0^T + bc0) — packed coalesced loads
    gemmM_mfma<3><<<dim3(B/64, 1), 256, 0, stream>>>(ueh, uel, lstmh, lstml, nullptr, wc0h, wc0l, bc0,
                                                     nullptr, nullptr, z0, nullptr, nullptr, 128, B);
    tail_k<<<B/64, THREADS, 0, stream>>>(z0, wtc1, bc1, wc2, bc2, (float*)d_out, B);

    (void)n_in; (void)out_size; (void)ws_size;
}